// Round 9
// baseline (294.635 us; speedup 1.0000x reference)
//
#include <hip/hip_runtime.h>
#include <math.h>

// B=4, S=1024, D=1024, H=16, KVH=4, HD=64, HIDDEN=1024, BLK=8
#define SEQ 1024
#define DIM 1024

using short8 = __attribute__((ext_vector_type(8))) short;
using f32x4  = __attribute__((ext_vector_type(4))) float;

__device__ __forceinline__ unsigned short f2bf(float f) {
  unsigned int u = __float_as_uint(f);
  u = (u + 0x7FFFu + ((u >> 16) & 1u)) >> 16;
  return (unsigned short)u;
}
__device__ __forceinline__ void load16_lds(const unsigned short* g, unsigned short* l) {
  __builtin_amdgcn_global_load_lds((const __attribute__((address_space(1))) void*)g,
                                   (__attribute__((address_space(3))) void*)l, 16, 0, 0);
}

// ---------------- weight cast (f32 -> bf16), 10 regions ----------------
// ilv: 0 = flat copy; 1/2 = row-interleave (dst row = src_row*2 + (ilv-1));
//      3 = silu(x) then flat store (vec -> SVEC).
struct CastArgs {
  const float* src[10];
  unsigned short* dst[10];
  int n[10];
  int ilv[10];
};
__global__ __launch_bounds__(256) void cast_weights(CastArgs a) {
  int r = blockIdx.y;
  int i4 = (blockIdx.x * 256 + threadIdx.x) * 4;
  if (i4 >= a.n[r]) return;
  float4 v = *(const float4*)(a.src[r] + i4);
  if (a.ilv[r] == 3) {
    v.x = v.x / (1.0f + expf(-v.x));
    v.y = v.y / (1.0f + expf(-v.y));
    v.z = v.z / (1.0f + expf(-v.z));
    v.w = v.w / (1.0f + expf(-v.w));
  }
  ushort4 o;
  o.x = f2bf(v.x); o.y = f2bf(v.y); o.z = f2bf(v.z); o.w = f2bf(v.w);
  size_t di = i4;
  if (a.ilv[r] == 1 || a.ilv[r] == 2)
    di = (size_t)((i4 >> 10) * 2 + (a.ilv[r] - 1)) * 1024 + (i4 & 1023);
  *(ushort4*)(a.dst[r] + di) = o;
}

// ---------------- MFMA GEMM: C[M,N] = A[M,K] @ W[N,K]^T (A,W bf16) ----------------
// R9: 128x64 tile, BK=32 -> LDS 24 KB -> 5-6 blocks/CU (R5-R8 invariant: every
// variant sat at <=3 blocks/CU with 48-64 KB LDS; per K-step a wave issues only
// ~110 cyc of work vs ~500-900 cyc load/barrier latency, so 3 waves/SIMD
// under-subscribe regardless of wait scheme). Fragment regs also halve.
// T4 counted-vmcnt 2-deep pipeline kept: 3 global_load_lds per wave per stage,
// own-wave vmcnt(3) BEFORE s_barrier => all waves' oldest stage landed when
// the last wave passes the barrier (cross-wave buffer-ready invariant).
// BK=32 row = 4 chunks of 16B; chunk swizzled cg = (slot&3) ^ (row&3) on the
// global source (global_load_lds forces linear LDS dest); reader chunk =
// q ^ (row&3) -- spreads a quad's 16 rows evenly over the 4 offset slots.
// EPI: 0 QKV(+RoPE)->bf16[N=1536]; V cols (colBlk>=1280) written TRANSPOSED
//        into VT[b][kvh][d][1024 keys] (outF reinterpreted).
//      1 +dual-bias->f32 (mod, N=6144)
//      2 x+gate*acc->f32 (h)       3 fused swiglu (interleaved u1/u3)->bf16 g[.,1024]
//      4 h+gate*acc->f32 (final)
template<int EPI>
__global__ __launch_bounds__(256, 5) void mfma_gemm(
    const unsigned short* __restrict__ A, const unsigned short* __restrict__ W,
    int M, int N, int K,
    float* __restrict__ outF, unsigned short* __restrict__ outBF,
    const float* __restrict__ aux1,   // bias1 / xres / hres
    const float* __restrict__ aux2,   // bias2 / mod-gate base (stride 6144)
    const float* __restrict__ fc, const float* __restrict__ fs)
{
  __shared__ unsigned short sA[2][128 * 32];  // 8 KB each
  __shared__ unsigned short sB[2][64 * 32];   // 4 KB each  (24 KB total)
  const int tid = threadIdx.x;
  const int lane = tid & 63;
  const int wv = tid >> 6;
  const int wr = wv >> 1;           // row half (64 rows)
  const int wc = wv & 1;            // col half (32 cols)
  const int rowBlk = blockIdx.y * 128;
  const int colBlk = blockIdx.x * 64;
  const int q = lane >> 4;          // quad
  const int cl = lane & 15;

  f32x4 acc[4][2] = {};

  auto stage = [&](int bf, int k0) {
#pragma unroll
    for (int j = 0; j < 2; ++j) {   // A: 128 rows x 4 chunks = 512 slots
      int slot = j * 256 + tid;
      int row = slot >> 2;
      int cg = (slot & 3) ^ (row & 3);
      load16_lds(A + (size_t)(rowBlk + row) * K + k0 + cg * 8, &sA[bf][slot * 8]);
    }
    {                               // B: 64 rows x 4 chunks = 256 slots
      int slot = tid;
      int row = slot >> 2;
      int cg = (slot & 3) ^ (row & 3);
      load16_lds(W + (size_t)(colBlk + row) * K + k0 + cg * 8, &sB[bf][slot * 8]);
    }
  };

  auto compute = [&](int bf) {
    short8 af[4], bfr[2];
#pragma unroll
    for (int t = 0; t < 4; ++t) {
      int row = wr * 64 + t * 16 + cl;
      af[t] = *(const short8*)&sA[bf][row * 32 + ((q ^ (row & 3)) * 8)];
    }
#pragma unroll
    for (int t = 0; t < 2; ++t) {
      int row = wc * 32 + t * 16 + cl;
      bfr[t] = *(const short8*)&sB[bf][row * 32 + ((q ^ (row & 3)) * 8)];
    }
#pragma unroll
    for (int tm = 0; tm < 4; ++tm)
#pragma unroll
      for (int tn = 0; tn < 2; ++tn)
        acc[tm][tn] = __builtin_amdgcn_mfma_f32_16x16x32_bf16(af[tm], bfr[tn], acc[tm][tn], 0, 0, 0);
  };

  // ---- 2-deep pipeline: vmcnt never drains to 0 in the loop ----
  stage(0, 0);          // 3 loads/wave
  stage(1, 32);         // 3 more
  int cur = 0;
  for (int k0 = 64; k0 < K; k0 += 32) {
    asm volatile("s_waitcnt vmcnt(3)" ::: "memory");  // own oldest 3 (= buf[cur]) landed
    __builtin_amdgcn_s_barrier();                     // => everyone's buf[cur] landed
    __builtin_amdgcn_sched_barrier(0);
    compute(cur);
    __builtin_amdgcn_s_barrier();                     // all waves done reading cur
    __builtin_amdgcn_sched_barrier(0);
    stage(cur, k0);                                   // restage cur 2 chunks ahead
    cur ^= 1;
  }
  asm volatile("s_waitcnt vmcnt(3)" ::: "memory");
  __builtin_amdgcn_s_barrier();
  __builtin_amdgcn_sched_barrier(0);
  compute(cur);
  asm volatile("s_waitcnt vmcnt(0)" ::: "memory");    // last buffer fully landed
  __builtin_amdgcn_s_barrier();
  __builtin_amdgcn_sched_barrier(0);
  compute(cur ^ 1);

  // epilogue: C/D layout col=lane&15, row=quad*4+reg (verified m89/m91)
#pragma unroll
  for (int tm = 0; tm < 4; ++tm) {
#pragma unroll
    for (int tn = 0; tn < 2; ++tn) {
      const int col = colBlk + wc * 32 + tn * 16 + cl;
      if constexpr (EPI == 0) {
        if (colBlk >= 1280) {
          // V block: store transposed VT[((b*4+kvh)*64 + d)*1024 + key]
          const int kvh2 = (col - 1280) >> 6;
          const int d2 = (col - 1280) & 63;
          const int row0 = rowBlk + wr * 64 + tm * 16 + q * 4;
          const int bb = row0 >> 10;
          const int key0 = row0 & (SEQ - 1);
          ushort4 o;
          o.x = f2bf(acc[tm][tn][0]); o.y = f2bf(acc[tm][tn][1]);
          o.z = f2bf(acc[tm][tn][2]); o.w = f2bf(acc[tm][tn][3]);
          *(ushort4*)((unsigned short*)outF +
                      (((size_t)(bb * 4 + kvh2) * 64 + d2) << 10) + key0) = o;
        } else {
#pragma unroll
          for (int r = 0; r < 4; ++r) {
            const int row = rowBlk + wr * 64 + tm * 16 + q * 4 + r;
            float v = acc[tm][tn][r];
            float other = __shfl_xor(v, 1);   // partner col (col^1), same row
            int s = row & (SEQ - 1);
            int t = (col & 63) >> 1;
            float cv = fc[s * 32 + t], sv = fs[s * 32 + t];
            v = ((col & 1) == 0) ? (v * cv - other * sv) : (other * sv + v * cv);
            outBF[(size_t)row * N + col] = f2bf(v);
          }
        }
      } else {
#pragma unroll
        for (int r = 0; r < 4; ++r) {
          const int row = rowBlk + wr * 64 + tm * 16 + q * 4 + r;
          float v = acc[tm][tn][r];
          if constexpr (EPI == 1) {
            float bb = (col < 3072) ? aux1[col] : aux2[col - 3072];
            outF[(size_t)row * N + col] = v + bb;
          } else if constexpr (EPI == 2 || EPI == 4) {
            int vr = (row >> 10) * 128 + ((row & (SEQ - 1)) >> 3);
            outF[(size_t)row * N + col] =
                aux1[(size_t)row * N + col] + aux2[(size_t)vr * 6144 + col] * v;
          } else if constexpr (EPI == 3) {
            // interleaved: even col = u1, odd col = u3; g = silu(u1)*u3
            float other = __shfl_xor(v, 1);
            if ((col & 1) == 0) {
              float g = v / (1.0f + expf(-v)) * other;
              outBF[(size_t)row * 1024 + (col >> 1)] = f2bf(g);
            }
          }
        }
      }
    }
  }
}

// ---------------- rmsnorm + modulation -> bf16 ----------------
__global__ __launch_bounds__(256) void rms_mod(
    const float* __restrict__ X, const float* __restrict__ w,
    const float* __restrict__ mod, int off, unsigned short* __restrict__ out)
{
  const int r = blockIdx.x;
  const int b = r >> 10, s = r & (SEQ - 1);
  const int vr = b * 128 + (s >> 3);
  const size_t base = (size_t)r * DIM;
  float v[4];
  float ss = 0.f;
#pragma unroll
  for (int p = 0; p < 4; ++p) {
    int c = threadIdx.x + p * 256;
    v[p] = X[base + c];
    ss += v[p] * v[p];
  }
#pragma unroll
  for (int o = 1; o < 64; o <<= 1) ss += __shfl_xor(ss, o);
  __shared__ float red[4];
  int lane = threadIdx.x & 63, wvv = threadIdx.x >> 6;
  if (lane == 0) red[wvv] = ss;
  __syncthreads();
  float total = red[0] + red[1] + red[2] + red[3];
  float rn = rsqrtf(total * (1.0f / 1024.0f) + 1e-6f);
  const float* mrow = mod + (size_t)vr * 6144 + off;
#pragma unroll
  for (int p = 0; p < 4; ++p) {
    int c = threadIdx.x + p * 256;
    out[base + c] = f2bf(v[p] * rn * w[c] * (1.0f + mrow[1024 + c]) + mrow[c]);
  }
}

// ---------------- MFMA flash block-causal attention ----------------
// QKV packed [4096][1536] bf16: q 0..1023, k 1024..1279 (V region unused);
// V comes transposed from VT[b][kvh][d][1024 keys] (written by QKV GEMM).
// Grid 1024, one q-tile per block; decode keeps all pr values on every XCD.
// Softmax without online max (scores O(1)-bounded, exp2 has 126b headroom).
// K/V staged via global_load_lds (pre-swizzled source), double-buffered,
// one barrier per KV tile. LDS = 40960 B -> 4 blocks/CU.
// s_setprio(1) around MFMA clusters (T5 regime: phase-diverse blocks).
__global__ __launch_bounds__(256, 4) void attn_mfma(
    const unsigned short* __restrict__ QKV, const unsigned short* __restrict__ VT,
    unsigned short* __restrict__ O)
{
  const int bid = blockIdx.x;
  const int half = bid >> 9;
  const int pr = (bid >> 6) & 7;
  const int h = (bid >> 2) & 15;
  const int b = bid & 3;
  const int qt = half ? (15 - pr) : pr;
  const int kvh = h >> 2;
  __shared__ unsigned short sK[2][64 * 64];   // [key][d], chunks XOR-swizzled by key&7
  __shared__ unsigned short sV[2][64 * 64];   // [d][key], chunks XOR-swizzled by d&7
  __shared__ unsigned short sP[4][16 * 64];   // per-wave P [qrow][key], XOR-swizzled
  const int tid = threadIdx.x;
  const int lane = tid & 63;
  const int w = tid >> 6;       // wave = q-row strip
  const int q = lane >> 4;      // quad
  const int cl = lane & 15;
  const float SCL = 0.125f * 1.44269504f;  // softmax in log2 domain

  // staging source pointers (kt=0); advance by constants per kt
  const unsigned short* kS[2];
  const unsigned short* vS[2];
#pragma unroll
  for (int i = 0; i < 2; ++i) {
    int slot = i * 256 + tid;
    int row = slot >> 3;
    int cg = (slot & 7) ^ (row & 7);
    kS[i] = QKV + (size_t)(b * SEQ + row) * 1536 + 1024 + kvh * 64 + cg * 8;
    vS[i] = VT + ((size_t)((b * 4 + kvh) * 64 + row) << 10) + cg * 8;
  }

  auto stage = [&](int bf, int kt) {
#pragma unroll
    for (int i = 0; i < 2; ++i) {
      load16_lds(kS[i] + (size_t)kt * (64 * 1536), &sK[bf][(i * 256 + tid) * 8]);
      load16_lds(vS[i] + kt * 64, &sV[bf][(i * 256 + tid) * 8]);
    }
  };

  short8 qf[2];
  {
    const size_t qrow = (size_t)(b * SEQ + qt * 64 + w * 16 + cl) * 1536 + h * 64;
#pragma unroll
    for (int s = 0; s < 2; ++s)
      qf[s] = *(const short8*)(QKV + qrow + s * 32 + q * 8);
  }

  f32x4 accO[4] = {};
  float l_p[4] = {0.f, 0.f, 0.f, 0.f};

  stage(0, 0);
  int cur = 0;
  for (int kt = 0; kt <= qt; ++kt) {
    __syncthreads();               // drains stage(cur); prev compute on cur^1 done
    if (kt < qt) stage(cur ^ 1, kt + 1);   // prefetch flies under compute(cur)

    f32x4 accS[4] = {};
    __builtin_amdgcn_s_setprio(1);
#pragma unroll
    for (int s = 0; s < 2; ++s) {
#pragma unroll
      for (int n = 0; n < 4; ++n) {
        int rowk = n * 16 + cl;
        short8 kf = *(const short8*)(&sK[cur][rowk * 64 + (((s * 4 + q) ^ (cl & 7)) * 8)]);
        accS[n] = __builtin_amdgcn_mfma_f32_16x16x32_bf16(qf[s], kf, accS[n], 0, 0, 0);
      }
    }
    __builtin_amdgcn_s_setprio(0);

    // p = exp2(s*SCL) (fixed max = 0), masked -> 0; accumulate l per-lane
    const bool diag = (kt == qt);
    const int qblk = w * 2 + (q >> 1);
#pragma unroll
    for (int n = 0; n < 4; ++n) {
      const bool msk = diag && (n * 2 + (cl >> 3)) > qblk;
#pragma unroll
      for (int r = 0; r < 4; ++r) {
        float pp = msk ? 0.f : exp2f(accS[n][r] * SCL);
        l_p[r] += pp;
        const int prow = q * 4 + r;
        sP[w][prow * 64 + ((n * 16 + cl) ^ ((prow & 7) * 8))] = f2bf(pp);
      }
    }

    short8 pf[2];
    pf[0] = *(const short8*)(&sP[w][cl * 64 + ((q * 8) ^ ((cl & 7) * 8))]);
    pf[1] = *(const short8*)(&sP[w][cl * 64 + ((32 + q * 8) ^ ((cl & 7) * 8))]);
    __builtin_amdgcn_s_setprio(1);
#pragma unroll
    for (int dn = 0; dn < 4; ++dn) {
#pragma unroll
      for (int s = 0; s < 2; ++s) {
        short8 vf = *(const short8*)(&sV[cur][(dn * 16 + cl) * 64 + (((s * 4 + q) ^ (cl & 7)) * 8)]);
        accO[dn] = __builtin_amdgcn_mfma_f32_16x16x32_bf16(pf[s], vf, accO[dn], 0, 0, 0);
      }
    }
    __builtin_amdgcn_s_setprio(0);
    cur ^= 1;
  }

  // final l reduction (cols of each row live on the 16 cl-lanes of a quad)
  float invl[4];
#pragma unroll
  for (int r = 0; r < 4; ++r) {
    float l = l_p[r];
    l += __shfl_xor(l, 1);
    l += __shfl_xor(l, 2);
    l += __shfl_xor(l, 4);
    l += __shfl_xor(l, 8);
    invl[r] = 1.0f / l;
  }
#pragma unroll
  for (int dn = 0; dn < 4; ++dn)
#pragma unroll
    for (int r = 0; r < 4; ++r) {
      int row = b * SEQ + qt * 64 + w * 16 + q * 4 + r;
      O[(size_t)row * DIM + h * 64 + dn * 16 + cl] = f2bf(accO[dn][r] * invl[r]);
    }
}

extern "C" void kernel_launch(void* const* d_in, const int* in_sizes, int n_in,
                              void* d_out, int out_size, void* d_ws, size_t ws_size,
                              hipStream_t stream)
{
  const float* x   = (const float*)d_in[0];
  const float* vec = (const float*)d_in[1];
  const float* wq  = (const float*)d_in[2];
  const float* wk  = (const float*)d_in[3];
  const float* wv  = (const float*)d_in[4];
  const float* wo  = (const float*)d_in[5];
  const float* w1  = (const float*)d_in[6];
  const float* w2  = (const float*)d_in[7];
  const float* w3  = (const float*)d_in[8];
  const float* maw = (const float*)d_in[9];
  const float* mab = (const float*)d_in[10];
  const float* mfw = (const float*)d_in[11];
  const float* mfb = (const float*)d_in[12];
  const float* n1w = (const float*)d_in[13];
  const float* n2w = (const float*)d_in[14];
  const float* fc  = (const float*)d_in[15];
  const float* fs  = (const float*)d_in[16];

  char* p = (char*)d_ws;
  auto takeU = [&](size_t elems) { unsigned short* r = (unsigned short*)p; p += elems * 2; return r; };
  auto takeF = [&](size_t elems) { float* r = (float*)p; p += elems * 4; return r; };

  unsigned short* WQKV = takeU((size_t)1536 * 1024);
  unsigned short* WOb  = takeU((size_t)1024 * 1024);
  unsigned short* W13  = takeU((size_t)2048 * 1024);   // row-interleaved w1/w3
  unsigned short* W2b  = takeU((size_t)1024 * 1024);
  unsigned short* WM   = takeU((size_t)6144 * 1024);   // [mod_attn_w | mod_ffn_w]
  unsigned short* SVEC = takeU((size_t)512 * 1024);
  float* MOD  = takeF((size_t)512 * 6144);             // [sh_a|sc_a|gt_a|sh_f|sc_f|gt_f]
  float* H    = takeF((size_t)4096 * 1024);
  unsigned short* XNb  = takeU((size_t)4096 * 1024);
  unsigned short* QKVb = takeU((size_t)4096 * 1536);
  unsigned short* VT   = takeU((size_t)16 * 64 * 1024); // [b][kvh][d][key] transposed V
  unsigned short* AOb  = takeU((size_t)4096 * 1024);
  unsigned short* HNb  = takeU((size_t)4096 * 1024);
  unsigned short* Gb  = AOb;   // alias: AO dead after WO gemm

  dim3 blk(256);

  CastArgs ca;
  ca.src[0] = wq;  ca.dst[0] = WQKV;                    ca.n[0] = 1024 * 1024; ca.ilv[0] = 0;
  ca.src[1] = wk;  ca.dst[1] = WQKV + 1024 * 1024;      ca.n[1] = 256 * 1024;  ca.ilv[1] = 0;
  ca.src[2] = wv;  ca.dst[2] = WQKV + 1280 * 1024;      ca.n[2] = 256 * 1024;  ca.ilv[2] = 0;
  ca.src[3] = wo;  ca.dst[3] = WOb;                     ca.n[3] = 1024 * 1024; ca.ilv[3] = 0;
  ca.src[4] = w1;  ca.dst[4] = W13;                     ca.n[4] = 1024 * 1024; ca.ilv[4] = 1;
  ca.src[5] = w3;  ca.dst[5] = W13;                     ca.n[5] = 1024 * 1024; ca.ilv[5] = 2;
  ca.src[6] = w2;  ca.dst[6] = W2b;                     ca.n[6] = 1024 * 1024; ca.ilv[6] = 0;
  ca.src[7] = maw; ca.dst[7] = WM;                      ca.n[7] = 3072 * 1024; ca.ilv[7] = 0;
  ca.src[8] = mfw; ca.dst[8] = WM + (size_t)3072 * 1024; ca.n[8] = 3072 * 1024; ca.ilv[8] = 0;
  ca.src[9] = vec; ca.dst[9] = SVEC;                    ca.n[9] = 512 * 1024;  ca.ilv[9] = 3;
  cast_weights<<<dim3(3072, 10), blk, 0, stream>>>(ca);

  // merged modulation GEMM -> f32 [512, 6144]  (128x64, 384 blocks)
  mfma_gemm<1><<<dim3(96, 4), blk, 0, stream>>>(SVEC, WM, 512, 6144, 1024,
      MOD, nullptr, mab, mfb, nullptr, nullptr);

  rms_mod<<<4096, blk, 0, stream>>>(x, n1w, MOD, 0, XNb);

  // fused QKV GEMM + RoPE -> packed bf16 [4096,1536]; V transposed to VT
  // (128x64, 768 blocks)
  mfma_gemm<0><<<dim3(24, 32), blk, 0, stream>>>(XNb, WQKV, 4096, 1536, 1024,
      (float*)VT, QKVb, nullptr, nullptr, fc, fs);

  attn_mfma<<<1024, blk, 0, stream>>>(QKVb, VT, AOb);

  // h = x + gate_a * (AO @ wo^T) -> f32  (128x64, 512 blocks)
  mfma_gemm<2><<<dim3(16, 32), blk, 0, stream>>>(AOb, WOb, 4096, 1024, 1024,
      H, nullptr, x, MOD + 2048, nullptr, nullptr);

  rms_mod<<<4096, blk, 0, stream>>>(H, n2w, MOD, 3072, HNb);

  // g = silu(hn@w1^T)*(hn@w3^T) fused swiglu -> bf16 [4096,1024]
  // (128x64, 1024 blocks)
  mfma_gemm<3><<<dim3(32, 32), blk, 0, stream>>>(HNb, W13, 4096, 2048, 1024,
      nullptr, Gb, nullptr, nullptr, nullptr, nullptr);

  // out = h + gate_f * (g @ w2^T) -> f32  (128x64, 512 blocks)
  mfma_gemm<4><<<dim3(16, 32), blk, 0, stream>>>(Gb, W2b, 4096, 1024, 1024,
      (float*)d_out, nullptr, H, MOD + 5120, nullptr, nullptr);
}

// Round 10
// 293.432 us; speedup vs baseline: 1.0041x; 1.0041x over previous
//
#include <hip/hip_runtime.h>
#include <math.h>

// B=4, S=1024, D=1024, H=16, KVH=4, HD=64, HIDDEN=1024, BLK=8
#define SEQ 1024
#define DIM 1024

using short8 = __attribute__((ext_vector_type(8))) short;
using f32x4  = __attribute__((ext_vector_type(4))) float;

__device__ __forceinline__ unsigned short f2bf(float f) {
  unsigned int u = __float_as_uint(f);
  u = (u + 0x7FFFu + ((u >> 16) & 1u)) >> 16;
  return (unsigned short)u;
}
__device__ __forceinline__ void load16_lds(const unsigned short* g, unsigned short* l) {
  __builtin_amdgcn_global_load_lds((const __attribute__((address_space(1))) void*)g,
                                   (__attribute__((address_space(3))) void*)l, 16, 0, 0);
}

// ---------------- weight cast (f32 -> bf16), 10 regions ----------------
// ilv: 0 = flat copy; 1/2 = row-interleave (dst row = src_row*2 + (ilv-1));
//      3 = silu(x) then flat store (vec -> SVEC).
struct CastArgs {
  const float* src[10];
  unsigned short* dst[10];
  int n[10];
  int ilv[10];
};
__global__ __launch_bounds__(256) void cast_weights(CastArgs a) {
  int r = blockIdx.y;
  int i4 = (blockIdx.x * 256 + threadIdx.x) * 4;
  if (i4 >= a.n[r]) return;
  float4 v = *(const float4*)(a.src[r] + i4);
  if (a.ilv[r] == 3) {
    v.x = v.x / (1.0f + expf(-v.x));
    v.y = v.y / (1.0f + expf(-v.y));
    v.z = v.z / (1.0f + expf(-v.z));
    v.w = v.w / (1.0f + expf(-v.w));
  }
  ushort4 o;
  o.x = f2bf(v.x); o.y = f2bf(v.y); o.z = f2bf(v.z); o.w = f2bf(v.w);
  size_t di = i4;
  if (a.ilv[r] == 1 || a.ilv[r] == 2)
    di = (size_t)((i4 >> 10) * 2 + (a.ilv[r] - 1)) * 1024 + (i4 & 1023);
  *(ushort4*)(a.dst[r] + di) = o;
}

// ---------------- MFMA GEMM: C[M,N] = A[M,K] @ W[N,K]^T (A,W bf16) ----------------
// 128x64 tile, BK=32, LDS 24 KB, T4 counted-vmcnt 2-deep pipeline (R9).
// R10 fix: R9's chunk swizzle (slot&3)^(row&3) gave a 4-way bank conflict
// (3.15M SQ_LDS_BANK_CONFLICT): bank = 16*(row&1) + chunk*4, and row&3 made
// rows r, r+4 alias. Swizzle on (row>>1)&3 instead: within any 8 consecutive
// rows the 4 even rows take chunks q^{0..3} (banks 0-15 once each) and the 4
// odd rows cover banks 16-31 -> every 8-lane group spans all 32 banks exactly
// once (the structure that measured 0 conflicts at BK=64).
// EPI: 0 QKV(+RoPE)->bf16[N=1536]; V cols (colBlk>=1280) written TRANSPOSED
//        into VT[b][kvh][d][1024 keys] (outF reinterpreted).
//      1 +dual-bias->f32 (mod, N=6144)
//      2 x+gate*acc->f32 (h)       3 fused swiglu (interleaved u1/u3)->bf16 g[.,1024]
//      4 h+gate*acc->f32 (final)
template<int EPI>
__global__ __launch_bounds__(256, 5) void mfma_gemm(
    const unsigned short* __restrict__ A, const unsigned short* __restrict__ W,
    int M, int N, int K,
    float* __restrict__ outF, unsigned short* __restrict__ outBF,
    const float* __restrict__ aux1,   // bias1 / xres / hres
    const float* __restrict__ aux2,   // bias2 / mod-gate base (stride 6144)
    const float* __restrict__ fc, const float* __restrict__ fs)
{
  __shared__ unsigned short sA[2][128 * 32];  // 8 KB each
  __shared__ unsigned short sB[2][64 * 32];   // 4 KB each  (24 KB total)
  const int tid = threadIdx.x;
  const int lane = tid & 63;
  const int wv = tid >> 6;
  const int wr = wv >> 1;           // row half (64 rows)
  const int wc = wv & 1;            // col half (32 cols)
  const int rowBlk = blockIdx.y * 128;
  const int colBlk = blockIdx.x * 64;
  const int q = lane >> 4;          // quad
  const int cl = lane & 15;

  f32x4 acc[4][2] = {};

  auto stage = [&](int bf, int k0) {
#pragma unroll
    for (int j = 0; j < 2; ++j) {   // A: 128 rows x 4 chunks = 512 slots
      int slot = j * 256 + tid;
      int row = slot >> 2;
      int cg = (slot & 3) ^ ((row >> 1) & 3);
      load16_lds(A + (size_t)(rowBlk + row) * K + k0 + cg * 8, &sA[bf][slot * 8]);
    }
    {                               // B: 64 rows x 4 chunks = 256 slots
      int slot = tid;
      int row = slot >> 2;
      int cg = (slot & 3) ^ ((row >> 1) & 3);
      load16_lds(W + (size_t)(colBlk + row) * K + k0 + cg * 8, &sB[bf][slot * 8]);
    }
  };

  auto compute = [&](int bf) {
    short8 af[4], bfr[2];
#pragma unroll
    for (int t = 0; t < 4; ++t) {
      int row = wr * 64 + t * 16 + cl;
      af[t] = *(const short8*)&sA[bf][row * 32 + ((q ^ ((row >> 1) & 3)) * 8)];
    }
#pragma unroll
    for (int t = 0; t < 2; ++t) {
      int row = wc * 32 + t * 16 + cl;
      bfr[t] = *(const short8*)&sB[bf][row * 32 + ((q ^ ((row >> 1) & 3)) * 8)];
    }
#pragma unroll
    for (int tm = 0; tm < 4; ++tm)
#pragma unroll
      for (int tn = 0; tn < 2; ++tn)
        acc[tm][tn] = __builtin_amdgcn_mfma_f32_16x16x32_bf16(af[tm], bfr[tn], acc[tm][tn], 0, 0, 0);
  };

  // ---- 2-deep pipeline: vmcnt never drains to 0 in the loop ----
  stage(0, 0);          // 3 loads/wave
  stage(1, 32);         // 3 more
  int cur = 0;
  for (int k0 = 64; k0 < K; k0 += 32) {
    asm volatile("s_waitcnt vmcnt(3)" ::: "memory");  // own oldest 3 (= buf[cur]) landed
    __builtin_amdgcn_s_barrier();                     // => everyone's buf[cur] landed
    __builtin_amdgcn_sched_barrier(0);
    compute(cur);
    __builtin_amdgcn_s_barrier();                     // all waves done reading cur
    __builtin_amdgcn_sched_barrier(0);
    stage(cur, k0);                                   // restage cur 2 chunks ahead
    cur ^= 1;
  }
  asm volatile("s_waitcnt vmcnt(3)" ::: "memory");
  __builtin_amdgcn_s_barrier();
  __builtin_amdgcn_sched_barrier(0);
  compute(cur);
  asm volatile("s_waitcnt vmcnt(0)" ::: "memory");    // last buffer fully landed
  __builtin_amdgcn_s_barrier();
  __builtin_amdgcn_sched_barrier(0);
  compute(cur ^ 1);

  // epilogue: C/D layout col=lane&15, row=quad*4+reg (verified m89/m91)
#pragma unroll
  for (int tm = 0; tm < 4; ++tm) {
#pragma unroll
    for (int tn = 0; tn < 2; ++tn) {
      const int col = colBlk + wc * 32 + tn * 16 + cl;
      if constexpr (EPI == 0) {
        if (colBlk >= 1280) {
          // V block: store transposed VT[((b*4+kvh)*64 + d)*1024 + key]
          const int kvh2 = (col - 1280) >> 6;
          const int d2 = (col - 1280) & 63;
          const int row0 = rowBlk + wr * 64 + tm * 16 + q * 4;
          const int bb = row0 >> 10;
          const int key0 = row0 & (SEQ - 1);
          ushort4 o;
          o.x = f2bf(acc[tm][tn][0]); o.y = f2bf(acc[tm][tn][1]);
          o.z = f2bf(acc[tm][tn][2]); o.w = f2bf(acc[tm][tn][3]);
          *(ushort4*)((unsigned short*)outF +
                      (((size_t)(bb * 4 + kvh2) * 64 + d2) << 10) + key0) = o;
        } else {
#pragma unroll
          for (int r = 0; r < 4; ++r) {
            const int row = rowBlk + wr * 64 + tm * 16 + q * 4 + r;
            float v = acc[tm][tn][r];
            float other = __shfl_xor(v, 1);   // partner col (col^1), same row
            int s = row & (SEQ - 1);
            int t = (col & 63) >> 1;
            float cv = fc[s * 32 + t], sv = fs[s * 32 + t];
            v = ((col & 1) == 0) ? (v * cv - other * sv) : (other * sv + v * cv);
            outBF[(size_t)row * N + col] = f2bf(v);
          }
        }
      } else {
#pragma unroll
        for (int r = 0; r < 4; ++r) {
          const int row = rowBlk + wr * 64 + tm * 16 + q * 4 + r;
          float v = acc[tm][tn][r];
          if constexpr (EPI == 1) {
            float bb = (col < 3072) ? aux1[col] : aux2[col - 3072];
            outF[(size_t)row * N + col] = v + bb;
          } else if constexpr (EPI == 2 || EPI == 4) {
            int vr = (row >> 10) * 128 + ((row & (SEQ - 1)) >> 3);
            outF[(size_t)row * N + col] =
                aux1[(size_t)row * N + col] + aux2[(size_t)vr * 6144 + col] * v;
          } else if constexpr (EPI == 3) {
            // interleaved: even col = u1, odd col = u3; g = silu(u1)*u3
            float other = __shfl_xor(v, 1);
            if ((col & 1) == 0) {
              float g = v / (1.0f + expf(-v)) * other;
              outBF[(size_t)row * 1024 + (col >> 1)] = f2bf(g);
            }
          }
        }
      }
    }
  }
}

// ---------------- rmsnorm + modulation -> bf16 ----------------
__global__ __launch_bounds__(256) void rms_mod(
    const float* __restrict__ X, const float* __restrict__ w,
    const float* __restrict__ mod, int off, unsigned short* __restrict__ out)
{
  const int r = blockIdx.x;
  const int b = r >> 10, s = r & (SEQ - 1);
  const int vr = b * 128 + (s >> 3);
  const size_t base = (size_t)r * DIM;
  float v[4];
  float ss = 0.f;
#pragma unroll
  for (int p = 0; p < 4; ++p) {
    int c = threadIdx.x + p * 256;
    v[p] = X[base + c];
    ss += v[p] * v[p];
  }
#pragma unroll
  for (int o = 1; o < 64; o <<= 1) ss += __shfl_xor(ss, o);
  __shared__ float red[4];
  int lane = threadIdx.x & 63, wvv = threadIdx.x >> 6;
  if (lane == 0) red[wvv] = ss;
  __syncthreads();
  float total = red[0] + red[1] + red[2] + red[3];
  float rn = rsqrtf(total * (1.0f / 1024.0f) + 1e-6f);
  const float* mrow = mod + (size_t)vr * 6144 + off;
#pragma unroll
  for (int p = 0; p < 4; ++p) {
    int c = threadIdx.x + p * 256;
    out[base + c] = f2bf(v[p] * rn * w[c] * (1.0f + mrow[1024 + c]) + mrow[c]);
  }
}

// ---------------- MFMA flash block-causal attention ----------------
// QKV packed [4096][1536] bf16: q 0..1023, k 1024..1279 (V region unused);
// V comes transposed from VT[b][kvh][d][1024 keys] (written by QKV GEMM).
// Grid 1024, one q-tile per block; decode keeps all pr values on every XCD.
// Softmax without online max (scores O(1)-bounded, exp2 has 126b headroom).
// K/V staged via global_load_lds (pre-swizzled source), double-buffered,
// one barrier per KV tile. LDS = 40960 B -> 4 blocks/CU.
// s_setprio(1) around MFMA clusters (T5 regime: phase-diverse blocks).
__global__ __launch_bounds__(256, 4) void attn_mfma(
    const unsigned short* __restrict__ QKV, const unsigned short* __restrict__ VT,
    unsigned short* __restrict__ O)
{
  const int bid = blockIdx.x;
  const int half = bid >> 9;
  const int pr = (bid >> 6) & 7;
  const int h = (bid >> 2) & 15;
  const int b = bid & 3;
  const int qt = half ? (15 - pr) : pr;
  const int kvh = h >> 2;
  __shared__ unsigned short sK[2][64 * 64];   // [key][d], chunks XOR-swizzled by key&7
  __shared__ unsigned short sV[2][64 * 64];   // [d][key], chunks XOR-swizzled by d&7
  __shared__ unsigned short sP[4][16 * 64];   // per-wave P [qrow][key], XOR-swizzled
  const int tid = threadIdx.x;
  const int lane = tid & 63;
  const int w = tid >> 6;       // wave = q-row strip
  const int q = lane >> 4;      // quad
  const int cl = lane & 15;
  const float SCL = 0.125f * 1.44269504f;  // softmax in log2 domain

  // staging source pointers (kt=0); advance by constants per kt
  const unsigned short* kS[2];
  const unsigned short* vS[2];
#pragma unroll
  for (int i = 0; i < 2; ++i) {
    int slot = i * 256 + tid;
    int row = slot >> 3;
    int cg = (slot & 7) ^ (row & 7);
    kS[i] = QKV + (size_t)(b * SEQ + row) * 1536 + 1024 + kvh * 64 + cg * 8;
    vS[i] = VT + ((size_t)((b * 4 + kvh) * 64 + row) << 10) + cg * 8;
  }

  auto stage = [&](int bf, int kt) {
#pragma unroll
    for (int i = 0; i < 2; ++i) {
      load16_lds(kS[i] + (size_t)kt * (64 * 1536), &sK[bf][(i * 256 + tid) * 8]);
      load16_lds(vS[i] + kt * 64, &sV[bf][(i * 256 + tid) * 8]);
    }
  };

  short8 qf[2];
  {
    const size_t qrow = (size_t)(b * SEQ + qt * 64 + w * 16 + cl) * 1536 + h * 64;
#pragma unroll
    for (int s = 0; s < 2; ++s)
      qf[s] = *(const short8*)(QKV + qrow + s * 32 + q * 8);
  }

  f32x4 accO[4] = {};
  float l_p[4] = {0.f, 0.f, 0.f, 0.f};

  stage(0, 0);
  int cur = 0;
  for (int kt = 0; kt <= qt; ++kt) {
    __syncthreads();               // drains stage(cur); prev compute on cur^1 done
    if (kt < qt) stage(cur ^ 1, kt + 1);   // prefetch flies under compute(cur)

    f32x4 accS[4] = {};
    __builtin_amdgcn_s_setprio(1);
#pragma unroll
    for (int s = 0; s < 2; ++s) {
#pragma unroll
      for (int n = 0; n < 4; ++n) {
        int rowk = n * 16 + cl;
        short8 kf = *(const short8*)(&sK[cur][rowk * 64 + (((s * 4 + q) ^ (cl & 7)) * 8)]);
        accS[n] = __builtin_amdgcn_mfma_f32_16x16x32_bf16(qf[s], kf, accS[n], 0, 0, 0);
      }
    }
    __builtin_amdgcn_s_setprio(0);

    // p = exp2(s*SCL) (fixed max = 0), masked -> 0; accumulate l per-lane
    const bool diag = (kt == qt);
    const int qblk = w * 2 + (q >> 1);
#pragma unroll
    for (int n = 0; n < 4; ++n) {
      const bool msk = diag && (n * 2 + (cl >> 3)) > qblk;
#pragma unroll
      for (int r = 0; r < 4; ++r) {
        float pp = msk ? 0.f : exp2f(accS[n][r] * SCL);
        l_p[r] += pp;
        const int prow = q * 4 + r;
        sP[w][prow * 64 + ((n * 16 + cl) ^ ((prow & 7) * 8))] = f2bf(pp);
      }
    }

    short8 pf[2];
    pf[0] = *(const short8*)(&sP[w][cl * 64 + ((q * 8) ^ ((cl & 7) * 8))]);
    pf[1] = *(const short8*)(&sP[w][cl * 64 + ((32 + q * 8) ^ ((cl & 7) * 8))]);
    __builtin_amdgcn_s_setprio(1);
#pragma unroll
    for (int dn = 0; dn < 4; ++dn) {
#pragma unroll
      for (int s = 0; s < 2; ++s) {
        short8 vf = *(const short8*)(&sV[cur][(dn * 16 + cl) * 64 + (((s * 4 + q) ^ (cl & 7)) * 8)]);
        accO[dn] = __builtin_amdgcn_mfma_f32_16x16x32_bf16(pf[s], vf, accO[dn], 0, 0, 0);
      }
    }
    __builtin_amdgcn_s_setprio(0);
    cur ^= 1;
  }

  // final l reduction (cols of each row live on the 16 cl-lanes of a quad)
  float invl[4];
#pragma unroll
  for (int r = 0; r < 4; ++r) {
    float l = l_p[r];
    l += __shfl_xor(l, 1);
    l += __shfl_xor(l, 2);
    l += __shfl_xor(l, 4);
    l += __shfl_xor(l, 8);
    invl[r] = 1.0f / l;
  }
#pragma unroll
  for (int dn = 0; dn < 4; ++dn)
#pragma unroll
    for (int r = 0; r < 4; ++r) {
      int row = b * SEQ + qt * 64 + w * 16 + q * 4 + r;
      O[(size_t)row * DIM + h * 64 + dn * 16 + cl] = f2bf(accO[dn][r] * invl[r]);
    }
}

extern "C" void kernel_launch(void* const* d_in, const int* in_sizes, int n_in,
                              void* d_out, int out_size, void* d_ws, size_t ws_size,
                              hipStream_t stream)
{
  const float* x   = (const float*)d_in[0];
  const float* vec = (const float*)d_in[1];
  const float* wq  = (const float*)d_in[2];
  const float* wk  = (const float*)d_in[3];
  const float* wv  = (const float*)d_in[4];
  const float* wo  = (const float*)d_in[5];
  const float* w1  = (const float*)d_in[6];
  const float* w2  = (const float*)d_in[7];
  const float* w3  = (const float*)d_in[8];
  const float* maw = (const float*)d_in[9];
  const float* mab = (const float*)d_in[10];
  const float* mfw = (const float*)d_in[11];
  const float* mfb = (const float*)d_in[12];
  const float* n1w = (const float*)d_in[13];
  const float* n2w = (const float*)d_in[14];
  const float* fc  = (const float*)d_in[15];
  const float* fs  = (const float*)d_in[16];

  char* p = (char*)d_ws;
  auto takeU = [&](size_t elems) { unsigned short* r = (unsigned short*)p; p += elems * 2; return r; };
  auto takeF = [&](size_t elems) { float* r = (float*)p; p += elems * 4; return r; };

  unsigned short* WQKV = takeU((size_t)1536 * 1024);
  unsigned short* WOb  = takeU((size_t)1024 * 1024);
  unsigned short* W13  = takeU((size_t)2048 * 1024);   // row-interleaved w1/w3
  unsigned short* W2b  = takeU((size_t)1024 * 1024);
  unsigned short* WM   = takeU((size_t)6144 * 1024);   // [mod_attn_w | mod_ffn_w]
  unsigned short* SVEC = takeU((size_t)512 * 1024);
  float* MOD  = takeF((size_t)512 * 6144);             // [sh_a|sc_a|gt_a|sh_f|sc_f|gt_f]
  float* H    = takeF((size_t)4096 * 1024);
  unsigned short* XNb  = takeU((size_t)4096 * 1024);
  unsigned short* QKVb = takeU((size_t)4096 * 1536);
  unsigned short* VT   = takeU((size_t)16 * 64 * 1024); // [b][kvh][d][key] transposed V
  unsigned short* AOb  = takeU((size_t)4096 * 1024);
  unsigned short* HNb  = takeU((size_t)4096 * 1024);
  unsigned short* Gb  = AOb;   // alias: AO dead after WO gemm

  dim3 blk(256);

  CastArgs ca;
  ca.src[0] = wq;  ca.dst[0] = WQKV;                    ca.n[0] = 1024 * 1024; ca.ilv[0] = 0;
  ca.src[1] = wk;  ca.dst[1] = WQKV + 1024 * 1024;      ca.n[1] = 256 * 1024;  ca.ilv[1] = 0;
  ca.src[2] = wv;  ca.dst[2] = WQKV + 1280 * 1024;      ca.n[2] = 256 * 1024;  ca.ilv[2] = 0;
  ca.src[3] = wo;  ca.dst[3] = WOb;                     ca.n[3] = 1024 * 1024; ca.ilv[3] = 0;
  ca.src[4] = w1;  ca.dst[4] = W13;                     ca.n[4] = 1024 * 1024; ca.ilv[4] = 1;
  ca.src[5] = w3;  ca.dst[5] = W13;                     ca.n[5] = 1024 * 1024; ca.ilv[5] = 2;
  ca.src[6] = w2;  ca.dst[6] = W2b;                     ca.n[6] = 1024 * 1024; ca.ilv[6] = 0;
  ca.src[7] = maw; ca.dst[7] = WM;                      ca.n[7] = 3072 * 1024; ca.ilv[7] = 0;
  ca.src[8] = mfw; ca.dst[8] = WM + (size_t)3072 * 1024; ca.n[8] = 3072 * 1024; ca.ilv[8] = 0;
  ca.src[9] = vec; ca.dst[9] = SVEC;                    ca.n[9] = 512 * 1024;  ca.ilv[9] = 3;
  cast_weights<<<dim3(3072, 10), blk, 0, stream>>>(ca);

  // merged modulation GEMM -> f32 [512, 6144]  (128x64, 384 blocks)
  mfma_gemm<1><<<dim3(96, 4), blk, 0, stream>>>(SVEC, WM, 512, 6144, 1024,
      MOD, nullptr, mab, mfb, nullptr, nullptr);

  rms_mod<<<4096, blk, 0, stream>>>(x, n1w, MOD, 0, XNb);

  // fused QKV GEMM + RoPE -> packed bf16 [4096,1536]; V transposed to VT
  // (128x64, 768 blocks)
  mfma_gemm<0><<<dim3(24, 32), blk, 0, stream>>>(XNb, WQKV, 4096, 1536, 1024,
      (float*)VT, QKVb, nullptr, nullptr, fc, fs);

  attn_mfma<<<1024, blk, 0, stream>>>(QKVb, VT, AOb);

  // h = x + gate_a * (AO @ wo^T) -> f32  (128x64, 512 blocks)
  mfma_gemm<2><<<dim3(16, 32), blk, 0, stream>>>(AOb, WOb, 4096, 1024, 1024,
      H, nullptr, x, MOD + 2048, nullptr, nullptr);

  rms_mod<<<4096, blk, 0, stream>>>(H, n2w, MOD, 3072, HNb);

  // g = silu(hn@w1^T)*(hn@w3^T) fused swiglu -> bf16 [4096,1024]
  // (128x64, 1024 blocks)
  mfma_gemm<3><<<dim3(32, 32), blk, 0, stream>>>(HNb, W13, 4096, 2048, 1024,
      nullptr, Gb, nullptr, nullptr, nullptr, nullptr);

  // out = h + gate_f * (g @ w2^T) -> f32  (128x64, 512 blocks)
  mfma_gemm<4><<<dim3(16, 32), blk, 0, stream>>>(Gb, W2b, 4096, 1024, 1024,
      (float*)d_out, nullptr, H, MOD + 5120, nullptr, nullptr);
}

// Round 11
// 279.824 us; speedup vs baseline: 1.0529x; 1.0486x over previous
//
#include <hip/hip_runtime.h>
#include <math.h>

// B=4, S=1024, D=1024, H=16, KVH=4, HD=64, HIDDEN=1024, BLK=8
#define SEQ 1024
#define DIM 1024

using short8 = __attribute__((ext_vector_type(8))) short;
using f32x4  = __attribute__((ext_vector_type(4))) float;

__device__ __forceinline__ unsigned short f2bf(float f) {
  unsigned int u = __float_as_uint(f);
  u = (u + 0x7FFFu + ((u >> 16) & 1u)) >> 16;
  return (unsigned short)u;
}
__device__ __forceinline__ void load16_lds(const unsigned short* g, unsigned short* l) {
  __builtin_amdgcn_global_load_lds((const __attribute__((address_space(1))) void*)g,
                                   (__attribute__((address_space(3))) void*)l, 16, 0, 0);
}

// ---------------- weight cast (f32 -> bf16), 10 regions ----------------
// ilv: 0 = flat copy; 1/2 = row-interleave (dst row = src_row*2 + (ilv-1));
//      3 = silu(x) then flat store (vec -> SVEC).
struct CastArgs {
  const float* src[10];
  unsigned short* dst[10];
  int n[10];
  int ilv[10];
};
__global__ __launch_bounds__(256) void cast_weights(CastArgs a) {
  int r = blockIdx.y;
  int i4 = (blockIdx.x * 256 + threadIdx.x) * 4;
  if (i4 >= a.n[r]) return;
  float4 v = *(const float4*)(a.src[r] + i4);
  if (a.ilv[r] == 3) {
    v.x = v.x / (1.0f + expf(-v.x));
    v.y = v.y / (1.0f + expf(-v.y));
    v.z = v.z / (1.0f + expf(-v.z));
    v.w = v.w / (1.0f + expf(-v.w));
  }
  ushort4 o;
  o.x = f2bf(v.x); o.y = f2bf(v.y); o.z = f2bf(v.z); o.w = f2bf(v.w);
  size_t di = i4;
  if (a.ilv[r] == 1 || a.ilv[r] == 2)
    di = (size_t)((i4 >> 10) * 2 + (a.ilv[r] - 1)) * 1024 + (i4 & 1023);
  *(ushort4*)(a.dst[r] + di) = o;
}

// ---------------- MFMA GEMM: C[M,N] = A[M,K] @ W[N,K]^T (A,W bf16) ----------------
// R11 = R6 config (best measured, 276.8us) + T1 XCD-aware block swizzle.
// R5-R10 established: {128x128@2/CU, 128x64@3/CU, 64x64@4/CU, counted-vmcnt,
// BK=32@5/CU} all within noise or worse -- the GEMMs are latency-bound with
// no pipe saturated. Remaining mechanism: FETCH_SIZE 34.9MB vs ~12MB ideal
// (FFN13) = A-panels re-fetched ~3x because consecutive bids (same row-panel)
// round-robin across XCDs. swz = (bid&7)*(nwg/8) + bid/8 (bijective; all
// grids %8==0) gives each XCD a contiguous run of row-panels: A-panel stays
// in its 4MB L2 across all col-tiles -> lower A-staging latency -> shorter
// per-K-step drain. BMxBN per shape as R6: 128x64 (QKV/FFN13), 64x64 (rest).
// BK=64, 2-stage LDS dbuf, K-chunk XOR-swizzled by row&7 on global source.
// EPI: 0 QKV(+RoPE)->bf16[N=1536]; V cols (colBlk>=1280) written TRANSPOSED
//        into VT[b][kvh][d][1024 keys] (outF reinterpreted).
//      1 +dual-bias->f32 (mod, N=6144)
//      2 x+gate*acc->f32 (h)       3 fused swiglu (interleaved u1/u3)->bf16 g[.,1024]
//      4 h+gate*acc->f32 (final)
template<int EPI, int BM, int BN>
__global__ __launch_bounds__(256, ((BM + BN) == 128 ? 4 : ((BM + BN) == 192 ? 3 : 2)))
void mfma_gemm(
    const unsigned short* __restrict__ A, const unsigned short* __restrict__ W,
    int M, int N, int K,
    float* __restrict__ outF, unsigned short* __restrict__ outBF,
    const float* __restrict__ aux1,   // bias1 / xres / hres
    const float* __restrict__ aux2,   // bias2 / mod-gate base (stride 6144)
    const float* __restrict__ fc, const float* __restrict__ fs)
{
  constexpr int MT = BM / 32;                 // acc rows per wave
  constexpr int NT = BN / 32;                 // acc cols per wave
  __shared__ unsigned short sA[2][BM * 64];
  __shared__ unsigned short sB[2][BN * 64];
  const int tid = threadIdx.x;
  const int lane = tid & 63;
  const int wv = tid >> 6;
  const int wr = wv >> 1;           // row half
  const int wc = wv & 1;            // col half
  // T1 XCD swizzle: contiguous row-panels per XCD (bijective, nwg%8==0)
  const int nwg = gridDim.x * gridDim.y;
  const int lbid = blockIdx.y * gridDim.x + blockIdx.x;
  const int swz = (lbid & 7) * (nwg >> 3) + (lbid >> 3);
  const int rowBlk = (swz / gridDim.x) * BM;
  const int colBlk = (swz % gridDim.x) * BN;
  const int q = lane >> 4;          // quad
  const int cl = lane & 15;

  f32x4 acc[MT][NT] = {};

  auto stage = [&](int bf, int k0) {
#pragma unroll
    for (int j = 0; j < MT; ++j) {
      int slot = j * 256 + tid;
      int row = slot >> 3;
      int cg = (slot & 7) ^ (row & 7);
      load16_lds(A + (size_t)(rowBlk + row) * K + k0 + cg * 8, &sA[bf][slot * 8]);
    }
#pragma unroll
    for (int j = 0; j < NT; ++j) {
      int slot = j * 256 + tid;
      int row = slot >> 3;
      int cg = (slot & 7) ^ (row & 7);
      load16_lds(W + (size_t)(colBlk + row) * K + k0 + cg * 8, &sB[bf][slot * 8]);
    }
  };

  auto compute = [&](int bf) {
    short8 af[MT][2], bfr[NT][2];
#pragma unroll
    for (int t = 0; t < MT; ++t) {
      int row = wr * (BM / 2) + t * 16 + cl;
#pragma unroll
      for (int s = 0; s < 2; ++s)
        af[t][s] = *(const short8*)&sA[bf][row * 64 + (((s * 4 + q) ^ (cl & 7)) * 8)];
    }
#pragma unroll
    for (int t = 0; t < NT; ++t) {
      int row = wc * (BN / 2) + t * 16 + cl;
#pragma unroll
      for (int s = 0; s < 2; ++s)
        bfr[t][s] = *(const short8*)&sB[bf][row * 64 + (((s * 4 + q) ^ (cl & 7)) * 8)];
    }
#pragma unroll
    for (int s = 0; s < 2; ++s)
#pragma unroll
      for (int tm = 0; tm < MT; ++tm)
#pragma unroll
        for (int tn = 0; tn < NT; ++tn)
          acc[tm][tn] = __builtin_amdgcn_mfma_f32_16x16x32_bf16(af[tm][s], bfr[tn][s], acc[tm][tn], 0, 0, 0);
  };

  stage(0, 0);
  int cur = 0;
  for (int k0 = 64; k0 < K; k0 += 64) {
    __syncthreads();          // drains cur's loads; prior compute on cur^1 done
    stage(cur ^ 1, k0);       // prefetch flies under compute(cur)
    compute(cur);
    cur ^= 1;
  }
  __syncthreads();
  compute(cur);

  // epilogue: C/D layout col=lane&15, row=quad*4+reg (verified m89/m91)
#pragma unroll
  for (int tm = 0; tm < MT; ++tm) {
#pragma unroll
    for (int tn = 0; tn < NT; ++tn) {
      const int col = colBlk + wc * (BN / 2) + tn * 16 + cl;
      if constexpr (EPI == 0) {
        if (colBlk >= 1280) {
          // V block: store transposed VT[((b*4+kvh)*64 + d)*1024 + key]
          const int kvh2 = (col - 1280) >> 6;
          const int d2 = (col - 1280) & 63;
          const int row0 = rowBlk + wr * (BM / 2) + tm * 16 + q * 4;
          const int bb = row0 >> 10;
          const int key0 = row0 & (SEQ - 1);
          ushort4 o;
          o.x = f2bf(acc[tm][tn][0]); o.y = f2bf(acc[tm][tn][1]);
          o.z = f2bf(acc[tm][tn][2]); o.w = f2bf(acc[tm][tn][3]);
          *(ushort4*)((unsigned short*)outF +
                      (((size_t)(bb * 4 + kvh2) * 64 + d2) << 10) + key0) = o;
        } else {
#pragma unroll
          for (int r = 0; r < 4; ++r) {
            const int row = rowBlk + wr * (BM / 2) + tm * 16 + q * 4 + r;
            float v = acc[tm][tn][r];
            float other = __shfl_xor(v, 1);   // partner col (col^1), same row
            int s = row & (SEQ - 1);
            int t = (col & 63) >> 1;
            float cv = fc[s * 32 + t], sv = fs[s * 32 + t];
            v = ((col & 1) == 0) ? (v * cv - other * sv) : (other * sv + v * cv);
            outBF[(size_t)row * N + col] = f2bf(v);
          }
        }
      } else {
#pragma unroll
        for (int r = 0; r < 4; ++r) {
          const int row = rowBlk + wr * (BM / 2) + tm * 16 + q * 4 + r;
          float v = acc[tm][tn][r];
          if constexpr (EPI == 1) {
            float bb = (col < 3072) ? aux1[col] : aux2[col - 3072];
            outF[(size_t)row * N + col] = v + bb;
          } else if constexpr (EPI == 2 || EPI == 4) {
            int vr = (row >> 10) * 128 + ((row & (SEQ - 1)) >> 3);
            outF[(size_t)row * N + col] =
                aux1[(size_t)row * N + col] + aux2[(size_t)vr * 6144 + col] * v;
          } else if constexpr (EPI == 3) {
            // interleaved: even col = u1, odd col = u3; g = silu(u1)*u3
            float other = __shfl_xor(v, 1);
            if ((col & 1) == 0) {
              float g = v / (1.0f + expf(-v)) * other;
              outBF[(size_t)row * 1024 + (col >> 1)] = f2bf(g);
            }
          }
        }
      }
    }
  }
}

// ---------------- rmsnorm + modulation -> bf16 ----------------
__global__ __launch_bounds__(256) void rms_mod(
    const float* __restrict__ X, const float* __restrict__ w,
    const float* __restrict__ mod, int off, unsigned short* __restrict__ out)
{
  const int r = blockIdx.x;
  const int b = r >> 10, s = r & (SEQ - 1);
  const int vr = b * 128 + (s >> 3);
  const size_t base = (size_t)r * DIM;
  float v[4];
  float ss = 0.f;
#pragma unroll
  for (int p = 0; p < 4; ++p) {
    int c = threadIdx.x + p * 256;
    v[p] = X[base + c];
    ss += v[p] * v[p];
  }
#pragma unroll
  for (int o = 1; o < 64; o <<= 1) ss += __shfl_xor(ss, o);
  __shared__ float red[4];
  int lane = threadIdx.x & 63, wvv = threadIdx.x >> 6;
  if (lane == 0) red[wvv] = ss;
  __syncthreads();
  float total = red[0] + red[1] + red[2] + red[3];
  float rn = rsqrtf(total * (1.0f / 1024.0f) + 1e-6f);
  const float* mrow = mod + (size_t)vr * 6144 + off;
#pragma unroll
  for (int p = 0; p < 4; ++p) {
    int c = threadIdx.x + p * 256;
    out[base + c] = f2bf(v[p] * rn * w[c] * (1.0f + mrow[1024 + c]) + mrow[c]);
  }
}

// ---------------- MFMA flash block-causal attention ----------------
// QKV packed [4096][1536] bf16: q 0..1023, k 1024..1279 (V region unused);
// V comes transposed from VT[b][kvh][d][1024 keys] (written by QKV GEMM).
// Grid 1024, one q-tile per block; decode keeps all pr values on every XCD.
// Softmax without online max (scores O(1)-bounded, exp2 has 126b headroom).
// K/V staged via global_load_lds (pre-swizzled source), double-buffered,
// one barrier per KV tile. LDS = 40960 B -> 4 blocks/CU.
// s_setprio(1) around MFMA clusters (T5 regime: phase-diverse blocks).
__global__ __launch_bounds__(256, 4) void attn_mfma(
    const unsigned short* __restrict__ QKV, const unsigned short* __restrict__ VT,
    unsigned short* __restrict__ O)
{
  const int bid = blockIdx.x;
  const int half = bid >> 9;
  const int pr = (bid >> 6) & 7;
  const int h = (bid >> 2) & 15;
  const int b = bid & 3;
  const int qt = half ? (15 - pr) : pr;
  const int kvh = h >> 2;
  __shared__ unsigned short sK[2][64 * 64];   // [key][d], chunks XOR-swizzled by key&7
  __shared__ unsigned short sV[2][64 * 64];   // [d][key], chunks XOR-swizzled by d&7
  __shared__ unsigned short sP[4][16 * 64];   // per-wave P [qrow][key], XOR-swizzled
  const int tid = threadIdx.x;
  const int lane = tid & 63;
  const int w = tid >> 6;       // wave = q-row strip
  const int q = lane >> 4;      // quad
  const int cl = lane & 15;
  const float SCL = 0.125f * 1.44269504f;  // softmax in log2 domain

  // staging source pointers (kt=0); advance by constants per kt
  const unsigned short* kS[2];
  const unsigned short* vS[2];
#pragma unroll
  for (int i = 0; i < 2; ++i) {
    int slot = i * 256 + tid;
    int row = slot >> 3;
    int cg = (slot & 7) ^ (row & 7);
    kS[i] = QKV + (size_t)(b * SEQ + row) * 1536 + 1024 + kvh * 64 + cg * 8;
    vS[i] = VT + ((size_t)((b * 4 + kvh) * 64 + row) << 10) + cg * 8;
  }

  auto stage = [&](int bf, int kt) {
#pragma unroll
    for (int i = 0; i < 2; ++i) {
      load16_lds(kS[i] + (size_t)kt * (64 * 1536), &sK[bf][(i * 256 + tid) * 8]);
      load16_lds(vS[i] + kt * 64, &sV[bf][(i * 256 + tid) * 8]);
    }
  };

  short8 qf[2];
  {
    const size_t qrow = (size_t)(b * SEQ + qt * 64 + w * 16 + cl) * 1536 + h * 64;
#pragma unroll
    for (int s = 0; s < 2; ++s)
      qf[s] = *(const short8*)(QKV + qrow + s * 32 + q * 8);
  }

  f32x4 accO[4] = {};
  float l_p[4] = {0.f, 0.f, 0.f, 0.f};

  stage(0, 0);
  int cur = 0;
  for (int kt = 0; kt <= qt; ++kt) {
    __syncthreads();               // drains stage(cur); prev compute on cur^1 done
    if (kt < qt) stage(cur ^ 1, kt + 1);   // prefetch flies under compute(cur)

    f32x4 accS[4] = {};
    __builtin_amdgcn_s_setprio(1);
#pragma unroll
    for (int s = 0; s < 2; ++s) {
#pragma unroll
      for (int n = 0; n < 4; ++n) {
        int rowk = n * 16 + cl;
        short8 kf = *(const short8*)(&sK[cur][rowk * 64 + (((s * 4 + q) ^ (cl & 7)) * 8)]);
        accS[n] = __builtin_amdgcn_mfma_f32_16x16x32_bf16(qf[s], kf, accS[n], 0, 0, 0);
      }
    }
    __builtin_amdgcn_s_setprio(0);

    // p = exp2(s*SCL) (fixed max = 0), masked -> 0; accumulate l per-lane
    const bool diag = (kt == qt);
    const int qblk = w * 2 + (q >> 1);
#pragma unroll
    for (int n = 0; n < 4; ++n) {
      const bool msk = diag && (n * 2 + (cl >> 3)) > qblk;
#pragma unroll
      for (int r = 0; r < 4; ++r) {
        float pp = msk ? 0.f : exp2f(accS[n][r] * SCL);
        l_p[r] += pp;
        const int prow = q * 4 + r;
        sP[w][prow * 64 + ((n * 16 + cl) ^ ((prow & 7) * 8))] = f2bf(pp);
      }
    }

    short8 pf[2];
    pf[0] = *(const short8*)(&sP[w][cl * 64 + ((q * 8) ^ ((cl & 7) * 8))]);
    pf[1] = *(const short8*)(&sP[w][cl * 64 + ((32 + q * 8) ^ ((cl & 7) * 8))]);
    __builtin_amdgcn_s_setprio(1);
#pragma unroll
    for (int dn = 0; dn < 4; ++dn) {
#pragma unroll
      for (int s = 0; s < 2; ++s) {
        short8 vf = *(const short8*)(&sV[cur][(dn * 16 + cl) * 64 + (((s * 4 + q) ^ (cl & 7)) * 8)]);
        accO[dn] = __builtin_amdgcn_mfma_f32_16x16x32_bf16(pf[s], vf, accO[dn], 0, 0, 0);
      }
    }
    __builtin_amdgcn_s_setprio(0);
    cur ^= 1;
  }

  // final l reduction (cols of each row live on the 16 cl-lanes of a quad)
  float invl[4];
#pragma unroll
  for (int r = 0; r < 4; ++r) {
    float l = l_p[r];
    l += __shfl_xor(l, 1);
    l += __shfl_xor(l, 2);
    l += __shfl_xor(l, 4);
    l += __shfl_xor(l, 8);
    invl[r] = 1.0f / l;
  }
#pragma unroll
  for (int dn = 0; dn < 4; ++dn)
#pragma unroll
    for (int r = 0; r < 4; ++r) {
      int row = b * SEQ + qt * 64 + w * 16 + q * 4 + r;
      O[(size_t)row * DIM + h * 64 + dn * 16 + cl] = f2bf(accO[dn][r] * invl[r]);
    }
}

extern "C" void kernel_launch(void* const* d_in, const int* in_sizes, int n_in,
                              void* d_out, int out_size, void* d_ws, size_t ws_size,
                              hipStream_t stream)
{
  const float* x   = (const float*)d_in[0];
  const float* vec = (const float*)d_in[1];
  const float* wq  = (const float*)d_in[2];
  const float* wk  = (const float*)d_in[3];
  const float* wv  = (const float*)d_in[4];
  const float* wo  = (const float*)d_in[5];
  const float* w1  = (const float*)d_in[6];
  const float* w2  = (const float*)d_in[7];
  const float* w3  = (const float*)d_in[8];
  const float* maw = (const float*)d_in[9];
  const float* mab = (const float*)d_in[10];
  const float* mfw = (const float*)d_in[11];
  const float* mfb = (const float*)d_in[12];
  const float* n1w = (const float*)d_in[13];
  const float* n2w = (const float*)d_in[14];
  const float* fc  = (const float*)d_in[15];
  const float* fs  = (const float*)d_in[16];

  char* p = (char*)d_ws;
  auto takeU = [&](size_t elems) { unsigned short* r = (unsigned short*)p; p += elems * 2; return r; };
  auto takeF = [&](size_t elems) { float* r = (float*)p; p += elems * 4; return r; };

  unsigned short* WQKV = takeU((size_t)1536 * 1024);
  unsigned short* WOb  = takeU((size_t)1024 * 1024);
  unsigned short* W13  = takeU((size_t)2048 * 1024);   // row-interleaved w1/w3
  unsigned short* W2b  = takeU((size_t)1024 * 1024);
  unsigned short* WM   = takeU((size_t)6144 * 1024);   // [mod_attn_w | mod_ffn_w]
  unsigned short* SVEC = takeU((size_t)512 * 1024);
  float* MOD  = takeF((size_t)512 * 6144);             // [sh_a|sc_a|gt_a|sh_f|sc_f|gt_f]
  float* H    = takeF((size_t)4096 * 1024);
  unsigned short* XNb  = takeU((size_t)4096 * 1024);
  unsigned short* QKVb = takeU((size_t)4096 * 1536);
  unsigned short* VT   = takeU((size_t)16 * 64 * 1024); // [b][kvh][d][key] transposed V
  unsigned short* AOb  = takeU((size_t)4096 * 1024);
  unsigned short* HNb  = takeU((size_t)4096 * 1024);
  unsigned short* Gb  = AOb;   // alias: AO dead after WO gemm

  dim3 blk(256);

  CastArgs ca;
  ca.src[0] = wq;  ca.dst[0] = WQKV;                    ca.n[0] = 1024 * 1024; ca.ilv[0] = 0;
  ca.src[1] = wk;  ca.dst[1] = WQKV + 1024 * 1024;      ca.n[1] = 256 * 1024;  ca.ilv[1] = 0;
  ca.src[2] = wv;  ca.dst[2] = WQKV + 1280 * 1024;      ca.n[2] = 256 * 1024;  ca.ilv[2] = 0;
  ca.src[3] = wo;  ca.dst[3] = WOb;                     ca.n[3] = 1024 * 1024; ca.ilv[3] = 0;
  ca.src[4] = w1;  ca.dst[4] = W13;                     ca.n[4] = 1024 * 1024; ca.ilv[4] = 1;
  ca.src[5] = w3;  ca.dst[5] = W13;                     ca.n[5] = 1024 * 1024; ca.ilv[5] = 2;
  ca.src[6] = w2;  ca.dst[6] = W2b;                     ca.n[6] = 1024 * 1024; ca.ilv[6] = 0;
  ca.src[7] = maw; ca.dst[7] = WM;                      ca.n[7] = 3072 * 1024; ca.ilv[7] = 0;
  ca.src[8] = mfw; ca.dst[8] = WM + (size_t)3072 * 1024; ca.n[8] = 3072 * 1024; ca.ilv[8] = 0;
  ca.src[9] = vec; ca.dst[9] = SVEC;                    ca.n[9] = 512 * 1024;  ca.ilv[9] = 3;
  cast_weights<<<dim3(3072, 10), blk, 0, stream>>>(ca);

  // merged modulation GEMM -> f32 [512, 6144]  (64x64 tile, 768 blocks, 3/CU)
  mfma_gemm<1, 64, 64><<<dim3(96, 8), blk, 0, stream>>>(SVEC, WM, 512, 6144, 1024,
      MOD, nullptr, mab, mfb, nullptr, nullptr);

  rms_mod<<<4096, blk, 0, stream>>>(x, n1w, MOD, 0, XNb);

  // fused QKV GEMM + RoPE -> packed bf16 [4096,1536]; V transposed to VT
  // (128x64 tile, 768 blocks, 3/CU)
  mfma_gemm<0, 128, 64><<<dim3(24, 32), blk, 0, stream>>>(XNb, WQKV, 4096, 1536, 1024,
      (float*)VT, QKVb, nullptr, nullptr, fc, fs);

  attn_mfma<<<1024, blk, 0, stream>>>(QKVb, VT, AOb);

  // h = x + gate_a * (AO @ wo^T) -> f32  (64x64 tile, 1024 blocks, 4/CU)
  mfma_gemm<2, 64, 64><<<dim3(16, 64), blk, 0, stream>>>(AOb, WOb, 4096, 1024, 1024,
      H, nullptr, x, MOD + 2048, nullptr, nullptr);

  rms_mod<<<4096, blk, 0, stream>>>(H, n2w, MOD, 3072, HNb);

  // g = silu(hn@w1^T)*(hn@w3^T) fused swiglu -> bf16 [4096,1024]
  // (128x64 tile, 1024 blocks, 3/CU)
  mfma_gemm<3, 128, 64><<<dim3(32, 32), blk, 0, stream>>>(HNb, W13, 4096, 2048, 1024,
      nullptr, Gb, nullptr, nullptr, nullptr, nullptr);

  // out = h + gate_f * (g @ w2^T) -> f32  (64x64 tile, 1024 blocks, 4/CU)
  mfma_gemm<4, 64, 64><<<dim3(16, 64), blk, 0, stream>>>(Gb, W2b, 4096, 1024, 1024,
      (float*)d_out, nullptr, H, MOD + 5120, nullptr, nullptr);
}

// Round 12
// 276.077 us; speedup vs baseline: 1.0672x; 1.0136x over previous
//
#include <hip/hip_runtime.h>
#include <math.h>

// B=4, S=1024, D=1024, H=16, KVH=4, HD=64, HIDDEN=1024, BLK=8
#define SEQ 1024
#define DIM 1024

using short8 = __attribute__((ext_vector_type(8))) short;
using f32x4  = __attribute__((ext_vector_type(4))) float;

__device__ __forceinline__ unsigned short f2bf(float f) {
  unsigned int u = __float_as_uint(f);
  u = (u + 0x7FFFu + ((u >> 16) & 1u)) >> 16;
  return (unsigned short)u;
}
__device__ __forceinline__ void load16_lds(const unsigned short* g, unsigned short* l) {
  __builtin_amdgcn_global_load_lds((const __attribute__((address_space(1))) void*)g,
                                   (__attribute__((address_space(3))) void*)l, 16, 0, 0);
}

// ---------------- weight cast (f32 -> bf16), 10 regions ----------------
// ilv: 0 = flat copy; 1/2 = row-interleave (dst row = src_row*2 + (ilv-1));
//      3 = silu(x) then flat store (vec -> SVEC).
struct CastArgs {
  const float* src[10];
  unsigned short* dst[10];
  int n[10];
  int ilv[10];
};
__global__ __launch_bounds__(256) void cast_weights(CastArgs a) {
  int r = blockIdx.y;
  int i4 = (blockIdx.x * 256 + threadIdx.x) * 4;
  if (i4 >= a.n[r]) return;
  float4 v = *(const float4*)(a.src[r] + i4);
  if (a.ilv[r] == 3) {
    v.x = v.x / (1.0f + expf(-v.x));
    v.y = v.y / (1.0f + expf(-v.y));
    v.z = v.z / (1.0f + expf(-v.z));
    v.w = v.w / (1.0f + expf(-v.w));
  }
  ushort4 o;
  o.x = f2bf(v.x); o.y = f2bf(v.y); o.z = f2bf(v.z); o.w = f2bf(v.w);
  size_t di = i4;
  if (a.ilv[r] == 1 || a.ilv[r] == 2)
    di = (size_t)((i4 >> 10) * 2 + (a.ilv[r] - 1)) * 1024 + (i4 & 1023);
  *(ushort4*)(a.dst[r] + di) = o;
}

// ---------------- MFMA GEMM: C[M,N] = A[M,K] @ W[N,K]^T (A,W bf16) ----------------
// R12 = exact R6 config (session best, 276.8us). Evidence ledger R5-R11:
// {128x128@2/CU, 128x64@3/CU, 64x64@4/CU, counted-vmcnt, BK=32@5/CU (with and
// without bank conflicts), XCD swizzle} all within [276.8, 294.6]; two
// mechanism-clean fixes (conflicts 3.15M->0, occupancy 21->40%) moved their
// counters exactly as predicted with zero duration change. The GEMMs are
// latency-bound (14% HBM, 15% MfmaUtil, 25% VALU) at a level the standard
// levers don't move beyond +-3% noise. BMxBN per shape: 128x64 (QKV/FFN13,
// 48KB LDS, 3/CU), 64x64 (mod/WO/W2, 32KB, 4/CU). BK=64, 2-stage LDS dbuf,
// K-chunk XOR-swizzled by row&7 on the global source (global_load_lds forces
// LDS dest = base + lane*16).
// EPI: 0 QKV(+RoPE)->bf16[N=1536]; V cols (colBlk>=1280) written TRANSPOSED
//        into VT[b][kvh][d][1024 keys] (outF reinterpreted).
//      1 +dual-bias->f32 (mod, N=6144)
//      2 x+gate*acc->f32 (h)       3 fused swiglu (interleaved u1/u3)->bf16 g[.,1024]
//      4 h+gate*acc->f32 (final)
template<int EPI, int BM, int BN>
__global__ __launch_bounds__(256, ((BM + BN) == 128 ? 4 : ((BM + BN) == 192 ? 3 : 2)))
void mfma_gemm(
    const unsigned short* __restrict__ A, const unsigned short* __restrict__ W,
    int M, int N, int K,
    float* __restrict__ outF, unsigned short* __restrict__ outBF,
    const float* __restrict__ aux1,   // bias1 / xres / hres
    const float* __restrict__ aux2,   // bias2 / mod-gate base (stride 6144)
    const float* __restrict__ fc, const float* __restrict__ fs)
{
  constexpr int MT = BM / 32;                 // acc rows per wave
  constexpr int NT = BN / 32;                 // acc cols per wave
  __shared__ unsigned short sA[2][BM * 64];
  __shared__ unsigned short sB[2][BN * 64];
  const int tid = threadIdx.x;
  const int lane = tid & 63;
  const int wv = tid >> 6;
  const int wr = wv >> 1;           // row half
  const int wc = wv & 1;            // col half
  const int rowBlk = blockIdx.y * BM;
  const int colBlk = blockIdx.x * BN;
  const int q = lane >> 4;          // quad
  const int cl = lane & 15;

  f32x4 acc[MT][NT] = {};

  auto stage = [&](int bf, int k0) {
#pragma unroll
    for (int j = 0; j < MT; ++j) {
      int slot = j * 256 + tid;
      int row = slot >> 3;
      int cg = (slot & 7) ^ (row & 7);
      load16_lds(A + (size_t)(rowBlk + row) * K + k0 + cg * 8, &sA[bf][slot * 8]);
    }
#pragma unroll
    for (int j = 0; j < NT; ++j) {
      int slot = j * 256 + tid;
      int row = slot >> 3;
      int cg = (slot & 7) ^ (row & 7);
      load16_lds(W + (size_t)(colBlk + row) * K + k0 + cg * 8, &sB[bf][slot * 8]);
    }
  };

  auto compute = [&](int bf) {
    short8 af[MT][2], bfr[NT][2];
#pragma unroll
    for (int t = 0; t < MT; ++t) {
      int row = wr * (BM / 2) + t * 16 + cl;
#pragma unroll
      for (int s = 0; s < 2; ++s)
        af[t][s] = *(const short8*)&sA[bf][row * 64 + (((s * 4 + q) ^ (cl & 7)) * 8)];
    }
#pragma unroll
    for (int t = 0; t < NT; ++t) {
      int row = wc * (BN / 2) + t * 16 + cl;
#pragma unroll
      for (int s = 0; s < 2; ++s)
        bfr[t][s] = *(const short8*)&sB[bf][row * 64 + (((s * 4 + q) ^ (cl & 7)) * 8)];
    }
#pragma unroll
    for (int s = 0; s < 2; ++s)
#pragma unroll
      for (int tm = 0; tm < MT; ++tm)
#pragma unroll
        for (int tn = 0; tn < NT; ++tn)
          acc[tm][tn] = __builtin_amdgcn_mfma_f32_16x16x32_bf16(af[tm][s], bfr[tn][s], acc[tm][tn], 0, 0, 0);
  };

  stage(0, 0);
  int cur = 0;
  for (int k0 = 64; k0 < K; k0 += 64) {
    __syncthreads();          // drains cur's loads; prior compute on cur^1 done
    stage(cur ^ 1, k0);       // prefetch flies under compute(cur)
    compute(cur);
    cur ^= 1;
  }
  __syncthreads();
  compute(cur);

  // epilogue: C/D layout col=lane&15, row=quad*4+reg (verified m89/m91)
#pragma unroll
  for (int tm = 0; tm < MT; ++tm) {
#pragma unroll
    for (int tn = 0; tn < NT; ++tn) {
      const int col = colBlk + wc * (BN / 2) + tn * 16 + cl;
      if constexpr (EPI == 0) {
        if (colBlk >= 1280) {
          // V block: store transposed VT[((b*4+kvh)*64 + d)*1024 + key]
          const int kvh2 = (col - 1280) >> 6;
          const int d2 = (col - 1280) & 63;
          const int row0 = rowBlk + wr * (BM / 2) + tm * 16 + q * 4;
          const int bb = row0 >> 10;
          const int key0 = row0 & (SEQ - 1);
          ushort4 o;
          o.x = f2bf(acc[tm][tn][0]); o.y = f2bf(acc[tm][tn][1]);
          o.z = f2bf(acc[tm][tn][2]); o.w = f2bf(acc[tm][tn][3]);
          *(ushort4*)((unsigned short*)outF +
                      (((size_t)(bb * 4 + kvh2) * 64 + d2) << 10) + key0) = o;
        } else {
#pragma unroll
          for (int r = 0; r < 4; ++r) {
            const int row = rowBlk + wr * (BM / 2) + tm * 16 + q * 4 + r;
            float v = acc[tm][tn][r];
            float other = __shfl_xor(v, 1);   // partner col (col^1), same row
            int s = row & (SEQ - 1);
            int t = (col & 63) >> 1;
            float cv = fc[s * 32 + t], sv = fs[s * 32 + t];
            v = ((col & 1) == 0) ? (v * cv - other * sv) : (other * sv + v * cv);
            outBF[(size_t)row * N + col] = f2bf(v);
          }
        }
      } else {
#pragma unroll
        for (int r = 0; r < 4; ++r) {
          const int row = rowBlk + wr * (BM / 2) + tm * 16 + q * 4 + r;
          float v = acc[tm][tn][r];
          if constexpr (EPI == 1) {
            float bb = (col < 3072) ? aux1[col] : aux2[col - 3072];
            outF[(size_t)row * N + col] = v + bb;
          } else if constexpr (EPI == 2 || EPI == 4) {
            int vr = (row >> 10) * 128 + ((row & (SEQ - 1)) >> 3);
            outF[(size_t)row * N + col] =
                aux1[(size_t)row * N + col] + aux2[(size_t)vr * 6144 + col] * v;
          } else if constexpr (EPI == 3) {
            // interleaved: even col = u1, odd col = u3; g = silu(u1)*u3
            float other = __shfl_xor(v, 1);
            if ((col & 1) == 0) {
              float g = v / (1.0f + expf(-v)) * other;
              outBF[(size_t)row * 1024 + (col >> 1)] = f2bf(g);
            }
          }
        }
      }
    }
  }
}

// ---------------- rmsnorm + modulation -> bf16 ----------------
__global__ __launch_bounds__(256) void rms_mod(
    const float* __restrict__ X, const float* __restrict__ w,
    const float* __restrict__ mod, int off, unsigned short* __restrict__ out)
{
  const int r = blockIdx.x;
  const int b = r >> 10, s = r & (SEQ - 1);
  const int vr = b * 128 + (s >> 3);
  const size_t base = (size_t)r * DIM;
  float v[4];
  float ss = 0.f;
#pragma unroll
  for (int p = 0; p < 4; ++p) {
    int c = threadIdx.x + p * 256;
    v[p] = X[base + c];
    ss += v[p] * v[p];
  }
#pragma unroll
  for (int o = 1; o < 64; o <<= 1) ss += __shfl_xor(ss, o);
  __shared__ float red[4];
  int lane = threadIdx.x & 63, wvv = threadIdx.x >> 6;
  if (lane == 0) red[wvv] = ss;
  __syncthreads();
  float total = red[0] + red[1] + red[2] + red[3];
  float rn = rsqrtf(total * (1.0f / 1024.0f) + 1e-6f);
  const float* mrow = mod + (size_t)vr * 6144 + off;
#pragma unroll
  for (int p = 0; p < 4; ++p) {
    int c = threadIdx.x + p * 256;
    out[base + c] = f2bf(v[p] * rn * w[c] * (1.0f + mrow[1024 + c]) + mrow[c]);
  }
}

// ---------------- MFMA flash block-causal attention ----------------
// QKV packed [4096][1536] bf16: q 0..1023, k 1024..1279 (V region unused);
// V comes transposed from VT[b][kvh][d][1024 keys] (written by QKV GEMM).
// Grid 1024, one q-tile per block; decode keeps all pr values on every XCD.
// Softmax without online max (scores O(1)-bounded, exp2 has 126b headroom).
// K/V staged via global_load_lds (pre-swizzled source), double-buffered,
// one barrier per KV tile. LDS = 40960 B -> 4 blocks/CU.
// s_setprio(1) around MFMA clusters (T5 regime: phase-diverse blocks).
__global__ __launch_bounds__(256, 4) void attn_mfma(
    const unsigned short* __restrict__ QKV, const unsigned short* __restrict__ VT,
    unsigned short* __restrict__ O)
{
  const int bid = blockIdx.x;
  const int half = bid >> 9;
  const int pr = (bid >> 6) & 7;
  const int h = (bid >> 2) & 15;
  const int b = bid & 3;
  const int qt = half ? (15 - pr) : pr;
  const int kvh = h >> 2;
  __shared__ unsigned short sK[2][64 * 64];   // [key][d], chunks XOR-swizzled by key&7
  __shared__ unsigned short sV[2][64 * 64];   // [d][key], chunks XOR-swizzled by d&7
  __shared__ unsigned short sP[4][16 * 64];   // per-wave P [qrow][key], XOR-swizzled
  const int tid = threadIdx.x;
  const int lane = tid & 63;
  const int w = tid >> 6;       // wave = q-row strip
  const int q = lane >> 4;      // quad
  const int cl = lane & 15;
  const float SCL = 0.125f * 1.44269504f;  // softmax in log2 domain

  // staging source pointers (kt=0); advance by constants per kt
  const unsigned short* kS[2];
  const unsigned short* vS[2];
#pragma unroll
  for (int i = 0; i < 2; ++i) {
    int slot = i * 256 + tid;
    int row = slot >> 3;
    int cg = (slot & 7) ^ (row & 7);
    kS[i] = QKV + (size_t)(b * SEQ + row) * 1536 + 1024 + kvh * 64 + cg * 8;
    vS[i] = VT + ((size_t)((b * 4 + kvh) * 64 + row) << 10) + cg * 8;
  }

  auto stage = [&](int bf, int kt) {
#pragma unroll
    for (int i = 0; i < 2; ++i) {
      load16_lds(kS[i] + (size_t)kt * (64 * 1536), &sK[bf][(i * 256 + tid) * 8]);
      load16_lds(vS[i] + kt * 64, &sV[bf][(i * 256 + tid) * 8]);
    }
  };

  short8 qf[2];
  {
    const size_t qrow = (size_t)(b * SEQ + qt * 64 + w * 16 + cl) * 1536 + h * 64;
#pragma unroll
    for (int s = 0; s < 2; ++s)
      qf[s] = *(const short8*)(QKV + qrow + s * 32 + q * 8);
  }

  f32x4 accO[4] = {};
  float l_p[4] = {0.f, 0.f, 0.f, 0.f};

  stage(0, 0);
  int cur = 0;
  for (int kt = 0; kt <= qt; ++kt) {
    __syncthreads();               // drains stage(cur); prev compute on cur^1 done
    if (kt < qt) stage(cur ^ 1, kt + 1);   // prefetch flies under compute(cur)

    f32x4 accS[4] = {};
    __builtin_amdgcn_s_setprio(1);
#pragma unroll
    for (int s = 0; s < 2; ++s) {
#pragma unroll
      for (int n = 0; n < 4; ++n) {
        int rowk = n * 16 + cl;
        short8 kf = *(const short8*)(&sK[cur][rowk * 64 + (((s * 4 + q) ^ (cl & 7)) * 8)]);
        accS[n] = __builtin_amdgcn_mfma_f32_16x16x32_bf16(qf[s], kf, accS[n], 0, 0, 0);
      }
    }
    __builtin_amdgcn_s_setprio(0);

    // p = exp2(s*SCL) (fixed max = 0), masked -> 0; accumulate l per-lane
    const bool diag = (kt == qt);
    const int qblk = w * 2 + (q >> 1);
#pragma unroll
    for (int n = 0; n < 4; ++n) {
      const bool msk = diag && (n * 2 + (cl >> 3)) > qblk;
#pragma unroll
      for (int r = 0; r < 4; ++r) {
        float pp = msk ? 0.f : exp2f(accS[n][r] * SCL);
        l_p[r] += pp;
        const int prow = q * 4 + r;
        sP[w][prow * 64 + ((n * 16 + cl) ^ ((prow & 7) * 8))] = f2bf(pp);
      }
    }

    short8 pf[2];
    pf[0] = *(const short8*)(&sP[w][cl * 64 + ((q * 8) ^ ((cl & 7) * 8))]);
    pf[1] = *(const short8*)(&sP[w][cl * 64 + ((32 + q * 8) ^ ((cl & 7) * 8))]);
    __builtin_amdgcn_s_setprio(1);
#pragma unroll
    for (int dn = 0; dn < 4; ++dn) {
#pragma unroll
      for (int s = 0; s < 2; ++s) {
        short8 vf = *(const short8*)(&sV[cur][(dn * 16 + cl) * 64 + (((s * 4 + q) ^ (cl & 7)) * 8)]);
        accO[dn] = __builtin_amdgcn_mfma_f32_16x16x32_bf16(pf[s], vf, accO[dn], 0, 0, 0);
      }
    }
    __builtin_amdgcn_s_setprio(0);
    cur ^= 1;
  }

  // final l reduction (cols of each row live on the 16 cl-lanes of a quad)
  float invl[4];
#pragma unroll
  for (int r = 0; r < 4; ++r) {
    float l = l_p[r];
    l += __shfl_xor(l, 1);
    l += __shfl_xor(l, 2);
    l += __shfl_xor(l, 4);
    l += __shfl_xor(l, 8);
    invl[r] = 1.0f / l;
  }
#pragma unroll
  for (int dn = 0; dn < 4; ++dn)
#pragma unroll
    for (int r = 0; r < 4; ++r) {
      int row = b * SEQ + qt * 64 + w * 16 + q * 4 + r;
      O[(size_t)row * DIM + h * 64 + dn * 16 + cl] = f2bf(accO[dn][r] * invl[r]);
    }
}

extern "C" void kernel_launch(void* const* d_in, const int* in_sizes, int n_in,
                              void* d_out, int out_size, void* d_ws, size_t ws_size,
                              hipStream_t stream)
{
  const float* x   = (const float*)d_in[0];
  const float* vec = (const float*)d_in[1];
  const float* wq  = (const float*)d_in[2];
  const float* wk  = (const float*)d_in[3];
  const float* wv  = (const float*)d_in[4];
  const float* wo  = (const float*)d_in[5];
  const float* w1  = (const float*)d_in[6];
  const float* w2  = (const float*)d_in[7];
  const float* w3  = (const float*)d_in[8];
  const float* maw = (const float*)d_in[9];
  const float* mab = (const float*)d_in[10];
  const float* mfw = (const float*)d_in[11];
  const float* mfb = (const float*)d_in[12];
  const float* n1w = (const float*)d_in[13];
  const float* n2w = (const float*)d_in[14];
  const float* fc  = (const float*)d_in[15];
  const float* fs  = (const float*)d_in[16];

  char* p = (char*)d_ws;
  auto takeU = [&](size_t elems) { unsigned short* r = (unsigned short*)p; p += elems * 2; return r; };
  auto takeF = [&](size_t elems) { float* r = (float*)p; p += elems * 4; return r; };

  unsigned short* WQKV = takeU((size_t)1536 * 1024);
  unsigned short* WOb  = takeU((size_t)1024 * 1024);
  unsigned short* W13  = takeU((size_t)2048 * 1024);   // row-interleaved w1/w3
  unsigned short* W2b  = takeU((size_t)1024 * 1024);
  unsigned short* WM   = takeU((size_t)6144 * 1024);   // [mod_attn_w | mod_ffn_w]
  unsigned short* SVEC = takeU((size_t)512 * 1024);
  float* MOD  = takeF((size_t)512 * 6144);             // [sh_a|sc_a|gt_a|sh_f|sc_f|gt_f]
  float* H    = takeF((size_t)4096 * 1024);
  unsigned short* XNb  = takeU((size_t)4096 * 1024);
  unsigned short* QKVb = takeU((size_t)4096 * 1536);
  unsigned short* VT   = takeU((size_t)16 * 64 * 1024); // [b][kvh][d][key] transposed V
  unsigned short* AOb  = takeU((size_t)4096 * 1024);
  unsigned short* HNb  = takeU((size_t)4096 * 1024);
  unsigned short* Gb  = AOb;   // alias: AO dead after WO gemm

  dim3 blk(256);

  CastArgs ca;
  ca.src[0] = wq;  ca.dst[0] = WQKV;                    ca.n[0] = 1024 * 1024; ca.ilv[0] = 0;
  ca.src[1] = wk;  ca.dst[1] = WQKV + 1024 * 1024;      ca.n[1] = 256 * 1024;  ca.ilv[1] = 0;
  ca.src[2] = wv;  ca.dst[2] = WQKV + 1280 * 1024;      ca.n[2] = 256 * 1024;  ca.ilv[2] = 0;
  ca.src[3] = wo;  ca.dst[3] = WOb;                     ca.n[3] = 1024 * 1024; ca.ilv[3] = 0;
  ca.src[4] = w1;  ca.dst[4] = W13;                     ca.n[4] = 1024 * 1024; ca.ilv[4] = 1;
  ca.src[5] = w3;  ca.dst[5] = W13;                     ca.n[5] = 1024 * 1024; ca.ilv[5] = 2;
  ca.src[6] = w2;  ca.dst[6] = W2b;                     ca.n[6] = 1024 * 1024; ca.ilv[6] = 0;
  ca.src[7] = maw; ca.dst[7] = WM;                      ca.n[7] = 3072 * 1024; ca.ilv[7] = 0;
  ca.src[8] = mfw; ca.dst[8] = WM + (size_t)3072 * 1024; ca.n[8] = 3072 * 1024; ca.ilv[8] = 0;
  ca.src[9] = vec; ca.dst[9] = SVEC;                    ca.n[9] = 512 * 1024;  ca.ilv[9] = 3;
  cast_weights<<<dim3(3072, 10), blk, 0, stream>>>(ca);

  // merged modulation GEMM -> f32 [512, 6144]  (64x64 tile, 768 blocks, 3/CU)
  mfma_gemm<1, 64, 64><<<dim3(96, 8), blk, 0, stream>>>(SVEC, WM, 512, 6144, 1024,
      MOD, nullptr, mab, mfb, nullptr, nullptr);

  rms_mod<<<4096, blk, 0, stream>>>(x, n1w, MOD, 0, XNb);

  // fused QKV GEMM + RoPE -> packed bf16 [4096,1536]; V transposed to VT
  // (128x64 tile, 768 blocks, 3/CU)
  mfma_gemm<0, 128, 64><<<dim3(24, 32), blk, 0, stream>>>(XNb, WQKV, 4096, 1536, 1024,
      (float*)VT, QKVb, nullptr, nullptr, fc, fs);

  attn_mfma<<<1024, blk, 0, stream>>>(QKVb, VT, AOb);

  // h = x + gate_a * (AO @ wo^T) -> f32  (64x64 tile, 1024 blocks, 4/CU)
  mfma_gemm<2, 64, 64><<<dim3(16, 64), blk, 0, stream>>>(AOb, WOb, 4096, 1024, 1024,
      H, nullptr, x, MOD + 2048, nullptr, nullptr);

  rms_mod<<<4096, blk, 0, stream>>>(H, n2w, MOD, 3072, HNb);

  // g = silu(hn@w1^T)*(hn@w3^T) fused swiglu -> bf16 [4096,1024]
  // (128x64 tile, 1024 blocks, 3/CU)
  mfma_gemm<3, 128, 64><<<dim3(32, 32), blk, 0, stream>>>(HNb, W13, 4096, 2048, 1024,
      nullptr, Gb, nullptr, nullptr, nullptr, nullptr);

  // out = h + gate_f * (g @ w2^T) -> f32  (64x64 tile, 1024 blocks, 4/CU)
  mfma_gemm<4, 64, 64><<<dim3(16, 64), blk, 0, stream>>>(Gb, W2b, 4096, 1024, 1024,
      (float*)d_out, nullptr, H, MOD + 5120, nullptr, nullptr);
}